// Round 1
// baseline (279.248 us; speedup 1.0000x reference)
//
#include <hip/hip_runtime.h>

// DiceLoss: predict,target fp32 [B=2, O=4, D=64, H=256, W=256]
// out = mean over (b,o) of [ sum_d valid*(1 - 2*num/den) / sum_d valid ]
// num = sum_hw sigmoid(p)*t ; den = sum_hw sigmoid(p) + sum_hw t + 1
// valid = (t[b,o,d,0] != -1)

constexpr int HW       = 256 * 256;     // 65536 elems per slice
constexpr int NSLICE   = 2 * 4 * 64;    // 512 slices
constexpr int NPAIR    = 2 * 4;         // 8 (b,o) pairs
constexpr int THREADS  = 1024;
constexpr int ITERS    = (HW / 4) / THREADS;  // 16 float4 loads per thread per array

__global__ __launch_bounds__(THREADS) void dice_stage1(
    const float* __restrict__ predict,
    const float* __restrict__ target,
    float* __restrict__ ws)   // ws[0..511] = dice*valid, ws[512..1023] = valid
{
    const int slice = blockIdx.x;
    const int tid   = threadIdx.x;
    const size_t base = (size_t)slice * HW;
    const float4* __restrict__ p4 = (const float4*)(predict + base);
    const float4* __restrict__ t4 = (const float4*)(target + base);

    float s_pt = 0.f, s_p = 0.f, s_t = 0.f;
#pragma unroll
    for (int k = 0; k < ITERS; ++k) {
        float4 pv = p4[k * THREADS + tid];
        float4 tv = t4[k * THREADS + tid];
        float e0 = 1.f / (1.f + __expf(-pv.x));
        float e1 = 1.f / (1.f + __expf(-pv.y));
        float e2 = 1.f / (1.f + __expf(-pv.z));
        float e3 = 1.f / (1.f + __expf(-pv.w));
        s_pt += e0 * tv.x;  s_pt += e1 * tv.y;
        s_pt += e2 * tv.z;  s_pt += e3 * tv.w;
        s_p  += (e0 + e1) + (e2 + e3);
        s_t  += (tv.x + tv.y) + (tv.z + tv.w);
    }

    // wave (64-lane) shuffle reduction
#pragma unroll
    for (int off = 32; off > 0; off >>= 1) {
        s_pt += __shfl_down(s_pt, off, 64);
        s_p  += __shfl_down(s_p,  off, 64);
        s_t  += __shfl_down(s_t,  off, 64);
    }

    __shared__ float l_pt[THREADS / 64];
    __shared__ float l_p [THREADS / 64];
    __shared__ float l_t [THREADS / 64];
    const int wave = tid >> 6;
    const int lane = tid & 63;
    if (lane == 0) { l_pt[wave] = s_pt; l_p[wave] = s_p; l_t[wave] = s_t; }
    __syncthreads();

    if (tid == 0) {
        float num = 0.f, sp = 0.f, st = 0.f;
#pragma unroll
        for (int w = 0; w < THREADS / 64; ++w) {
            num += l_pt[w]; sp += l_p[w]; st += l_t[w];
        }
        float den  = sp + st + 1.0f;                     // SMOOTH = 1
        float dice = 1.0f - 2.0f * num / den;
        float valid = (target[base] != -1.0f) ? 1.0f : 0.0f;
        ws[slice]          = dice * valid;
        ws[NSLICE + slice] = valid;
    }
}

__global__ __launch_bounds__(NSLICE) void dice_stage2(
    const float* __restrict__ ws, float* __restrict__ out)
{
    const int tid = threadIdx.x;          // 0..511, wave w = (b,o) pair w (D=64)
    float dv = ws[tid];
    float v  = ws[NSLICE + tid];
#pragma unroll
    for (int off = 32; off > 0; off >>= 1) {
        dv += __shfl_down(dv, off, 64);
        v  += __shfl_down(v,  off, 64);
    }
    __shared__ float pair_avg[NPAIR];
    const int wave = tid >> 6;
    const int lane = tid & 63;
    if (lane == 0) pair_avg[wave] = dv / v;
    __syncthreads();
    if (tid == 0) {
        float s = 0.f;
#pragma unroll
        for (int w = 0; w < NPAIR; ++w) s += pair_avg[w];
        out[0] = s * (1.0f / NPAIR);
    }
}

extern "C" void kernel_launch(void* const* d_in, const int* in_sizes, int n_in,
                              void* d_out, int out_size, void* d_ws, size_t ws_size,
                              hipStream_t stream) {
    const float* predict = (const float*)d_in[0];
    const float* target  = (const float*)d_in[1];
    float* ws  = (float*)d_ws;
    float* out = (float*)d_out;

    dice_stage1<<<NSLICE, THREADS, 0, stream>>>(predict, target, ws);
    dice_stage2<<<1, NSLICE, 0, stream>>>(ws, out);
}

// Round 2
// 276.831 us; speedup vs baseline: 1.0087x; 1.0087x over previous
//
#include <hip/hip_runtime.h>

// DiceLoss: predict,target fp32 [B=2, O=4, D=64, H=256, W=256]
// out = mean over (b,o) of [ sum_d valid*(1 - 2*num/den) / sum_d valid ]
// num = sum_hw sigmoid(p)*t ; den = sum_hw sigmoid(p) + sum_hw t + 1
// valid = (t[b,o,d,0] != -1)

constexpr int HW       = 256 * 256;     // 65536 elems per slice
constexpr int NSLICE   = 2 * 4 * 64;    // 512 slices
constexpr int NPAIR    = 2 * 4;         // 8 (b,o) pairs
constexpr int THREADS  = 1024;
constexpr int ITERS    = (HW / 4) / THREADS;  // 16 float4 loads per thread per array
constexpr int BATCH    = 8;                   // loads kept in flight per wait

__global__ __launch_bounds__(THREADS) void dice_stage1(
    const float* __restrict__ predict,
    const float* __restrict__ target,
    float* __restrict__ ws)   // ws[0..511] = dice*valid, ws[512..1023] = valid
{
    const int slice = blockIdx.x;
    const int tid   = threadIdx.x;
    const size_t base = (size_t)slice * HW;
    const float4* __restrict__ p4 = (const float4*)(predict + base);
    const float4* __restrict__ t4 = (const float4*)(target + base);

    float s_pt0 = 0.f, s_pt1 = 0.f, s_p0 = 0.f, s_p1 = 0.f, s_t0 = 0.f, s_t1 = 0.f;

    for (int k0 = 0; k0 < ITERS; k0 += BATCH) {
        float4 pv[BATCH], tv[BATCH];
        // Issue all 2*BATCH loads before any consumption -> high vmcnt MLP.
#pragma unroll
        for (int j = 0; j < BATCH; ++j)
            pv[j] = p4[(size_t)(k0 + j) * THREADS + tid];
#pragma unroll
        for (int j = 0; j < BATCH; ++j)
            tv[j] = t4[(size_t)(k0 + j) * THREADS + tid];
#pragma unroll
        for (int j = 0; j < BATCH; ++j) {
            float e0 = 1.f / (1.f + __expf(-pv[j].x));
            float e1 = 1.f / (1.f + __expf(-pv[j].y));
            float e2 = 1.f / (1.f + __expf(-pv[j].z));
            float e3 = 1.f / (1.f + __expf(-pv[j].w));
            s_pt0 += e0 * tv[j].x + e1 * tv[j].y;
            s_pt1 += e2 * tv[j].z + e3 * tv[j].w;
            s_p0  += e0 + e1;
            s_p1  += e2 + e3;
            s_t0  += tv[j].x + tv[j].y;
            s_t1  += tv[j].z + tv[j].w;
        }
    }

    float s_pt = s_pt0 + s_pt1;
    float s_p  = s_p0 + s_p1;
    float s_t  = s_t0 + s_t1;

    // wave (64-lane) shuffle reduction
#pragma unroll
    for (int off = 32; off > 0; off >>= 1) {
        s_pt += __shfl_down(s_pt, off, 64);
        s_p  += __shfl_down(s_p,  off, 64);
        s_t  += __shfl_down(s_t,  off, 64);
    }

    __shared__ float l_pt[THREADS / 64];
    __shared__ float l_p [THREADS / 64];
    __shared__ float l_t [THREADS / 64];
    const int wave = tid >> 6;
    const int lane = tid & 63;
    if (lane == 0) { l_pt[wave] = s_pt; l_p[wave] = s_p; l_t[wave] = s_t; }
    __syncthreads();

    if (tid == 0) {
        float num = 0.f, sp = 0.f, st = 0.f;
#pragma unroll
        for (int w = 0; w < THREADS / 64; ++w) {
            num += l_pt[w]; sp += l_p[w]; st += l_t[w];
        }
        float den  = sp + st + 1.0f;                     // SMOOTH = 1
        float dice = 1.0f - 2.0f * num / den;
        float valid = (target[base] != -1.0f) ? 1.0f : 0.0f;
        ws[slice]          = dice * valid;
        ws[NSLICE + slice] = valid;
    }
}

__global__ __launch_bounds__(NSLICE) void dice_stage2(
    const float* __restrict__ ws, float* __restrict__ out)
{
    const int tid = threadIdx.x;          // 0..511, wave w = (b,o) pair w (D=64)
    float dv = ws[tid];
    float v  = ws[NSLICE + tid];
#pragma unroll
    for (int off = 32; off > 0; off >>= 1) {
        dv += __shfl_down(dv, off, 64);
        v  += __shfl_down(v,  off, 64);
    }
    __shared__ float pair_avg[NPAIR];
    const int wave = tid >> 6;
    const int lane = tid & 63;
    if (lane == 0) pair_avg[wave] = dv / v;
    __syncthreads();
    if (tid == 0) {
        float s = 0.f;
#pragma unroll
        for (int w = 0; w < NPAIR; ++w) s += pair_avg[w];
        out[0] = s * (1.0f / NPAIR);
    }
}

extern "C" void kernel_launch(void* const* d_in, const int* in_sizes, int n_in,
                              void* d_out, int out_size, void* d_ws, size_t ws_size,
                              hipStream_t stream) {
    const float* predict = (const float*)d_in[0];
    const float* target  = (const float*)d_in[1];
    float* ws  = (float*)d_ws;
    float* out = (float*)d_out;

    dice_stage1<<<NSLICE, THREADS, 0, stream>>>(predict, target, ws);
    dice_stage2<<<1, NSLICE, 0, stream>>>(ws, out);
}